// Round 2
// baseline (339.069 us; speedup 1.0000x reference)
//
#include <hip/hip_runtime.h>
#include <hip/hip_bf16.h>
#include <stdint.h>

// SoftTree: x(65536x512) f32, gw(512x255) f32, gb(255) f32, z(256x256) f32 -> out(65536x256) f32
// g = sigmoid(x@gw+gb); leaf = depth-8 tree products of g / (1-g); out = leaf @ z^T.
//
// R2: barrier-free GEMM1 with an explicit register pipeline.
//   - __launch_bounds__(512,2): 256 regs/wave (8 waves/CU) so the pipeline fits in registers.
//   - x (HBM/L3 stream): prefetch DEPTH 4 steps ahead in a rotating 4-slot register queue
//     (64 VGPRs) — covers ~800 cycles of load latency.
//   - B (gwt, 256KB L2-resident): prefetch 1 step ahead (32 VGPRs), read straight from global.
//   - K-loop fully unrolled (16 steps of K=32) so all queue indices are compile-time.
// LDS holds only the gates buffer (64x258 f32 = 66 KB).

typedef short bf16x8 __attribute__((ext_vector_type(8)));
typedef float f32x4  __attribute__((ext_vector_type(4)));

__device__ __forceinline__ unsigned short f2bf(float f) {
    union { float f; uint32_t u; } c; c.f = f;
    uint32_t u = c.u;
    return (unsigned short)((u + 0x7FFFu + ((u >> 16) & 1u)) >> 16);
}

__device__ __forceinline__ uint32_t pkbf(float a, float b) {
    union { __hip_bfloat162 h; uint32_t u; } cv;
    cv.h = __float22bfloat162_rn(make_float2(a, b));   // v_cvt_pk_bf16_f32 on gfx950
    return cv.u;
}

// ---- prep: blocks 0..31 transpose gw (512x255 f32, gate-fast) -> gwt bf16 [gate][k] (256x512, row255=0)
//            blocks 32..95: z (256x256 f32) -> zb bf16
__global__ __launch_bounds__(256) void softtree_prep(
    const float* __restrict__ gw, const float* __restrict__ z,
    unsigned short* __restrict__ gwt, unsigned short* __restrict__ zb)
{
    if (blockIdx.x < 32) {
        __shared__ float tsm[64][65];
        const int k0 = (blockIdx.x >> 2) * 64;
        const int n0 = (blockIdx.x & 3) * 64;
        const int r = threadIdx.x >> 6;   // 0..3
        const int c = threadIdx.x & 63;   // 0..63
        const int n = n0 + c;
        #pragma unroll
        for (int i = 0; i < 16; ++i) {
            int kk = r + i * 4;
            tsm[kk][c] = (n < 255) ? gw[(size_t)(k0 + kk) * 255 + n] : 0.0f;
        }
        __syncthreads();
        #pragma unroll
        for (int i = 0; i < 16; ++i) {
            int nn = r + i * 4;           // local gate index
            gwt[(size_t)(n0 + nn) * 512 + k0 + c] = f2bf(tsm[c][nn]);
        }
    } else {
        int base = (blockIdx.x - 32) * 1024 + threadIdx.x * 4;
        const float4 v = *(const float4*)(z + base);
        ushort4 o;
        o.x = f2bf(v.x); o.y = f2bf(v.y); o.z = f2bf(v.z); o.w = f2bf(v.w);
        *(ushort4*)(zb + base) = o;
    }
}

// ---- main: 512 threads (8 waves), 2 row-tiles of 64 per block, grid 512.
// Wave (wr = wv&3, wc = wv>>2): rows 16*wr + l15 (both tiles), gates 128*wc + nt*16 + l15.
__global__ __launch_bounds__(512, 2) void softtree_main(
    const float* __restrict__ x, const float* __restrict__ gb,
    const unsigned short* __restrict__ gwt, const unsigned short* __restrict__ zb,
    float* __restrict__ out)
{
    __shared__ float gs[64 * 258];   // 66048 B: gates for one 64-row tile, stride 258

    const int tid  = threadIdx.x;
    const int lane = tid & 63;
    const int wv   = tid >> 6;
    const int q    = lane >> 4;
    const int l15  = lane & 15;
    const int wr   = wv & 3;
    const int wc   = wv >> 2;
    const int R0   = blockIdx.x * 128;

    // A-frag base: row = R0 + t*64 + 16*wr + l15, frag k-elems = 32*sidx + 8*q + j
    const float* xr = x + (size_t)(R0 + 16 * wr + l15) * 512 + 8 * q;
    // B-frag base: gate = 128*wc + nt*16 + l15, same k mapping (gwt is [gate][k] bf16)
    const unsigned short* bp = gwt + (size_t)(128 * wc + l15) * 512 + 8 * q;

    f32x4 acc[2][8];
    #pragma unroll
    for (int t = 0; t < 2; ++t)
        #pragma unroll
        for (int i = 0; i < 8; ++i) acc[t][i] = (f32x4){0.f, 0.f, 0.f, 0.f};

    // ---- GEMM1: barrier-free, register-pipelined K-loop (16 steps of K=32)
    float4 xq[4][4];     // rotating x queue: slot = sidx&3, [0..1]=tile0, [2..3]=tile1
    bf16x8 bq[2][8];     // B double buffer: slot = sidx&1

    #pragma unroll
    for (int p = 0; p < 4; ++p) {
        const int ko = 32 * p;
        xq[p][0] = *(const float4*)(xr + ko);
        xq[p][1] = *(const float4*)(xr + ko + 4);
        xq[p][2] = *(const float4*)(xr + 32768 + ko);
        xq[p][3] = *(const float4*)(xr + 32768 + ko + 4);
    }
    #pragma unroll
    for (int nt = 0; nt < 8; ++nt)
        bq[0][nt] = *(const bf16x8*)(bp + nt * 8192);

    #pragma unroll
    for (int sidx = 0; sidx < 16; ++sidx) {
        const int slot = sidx & 3;
        const int cb   = sidx & 1;

        // issue next step's B-frags (L2-resident, 1-step lead)
        if (sidx + 1 < 16) {
            const int ko = 32 * (sidx + 1);
            #pragma unroll
            for (int nt = 0; nt < 8; ++nt)
                bq[cb ^ 1][nt] = *(const bf16x8*)(bp + nt * 8192 + ko);
        }

        // convert current x slot (loaded 4 steps ago) to bf16 A-frags
        bf16x8 a0, a1;
        {
            union { bf16x8 v; uint32_t u[4]; } pk;
            pk.u[0] = pkbf(xq[slot][0].x, xq[slot][0].y);
            pk.u[1] = pkbf(xq[slot][0].z, xq[slot][0].w);
            pk.u[2] = pkbf(xq[slot][1].x, xq[slot][1].y);
            pk.u[3] = pkbf(xq[slot][1].z, xq[slot][1].w);
            a0 = pk.v;
            pk.u[0] = pkbf(xq[slot][2].x, xq[slot][2].y);
            pk.u[1] = pkbf(xq[slot][2].z, xq[slot][2].w);
            pk.u[2] = pkbf(xq[slot][3].x, xq[slot][3].y);
            pk.u[3] = pkbf(xq[slot][3].z, xq[slot][3].w);
            a1 = pk.v;
        }

        // refill the freed slot with x for sidx+4 (stays in flight ~4 steps)
        if (sidx + 4 < 16) {
            const int ko = 32 * (sidx + 4);
            xq[slot][0] = *(const float4*)(xr + ko);
            xq[slot][1] = *(const float4*)(xr + ko + 4);
            xq[slot][2] = *(const float4*)(xr + 32768 + ko);
            xq[slot][3] = *(const float4*)(xr + 32768 + ko + 4);
        }

        // MFMA for this step
        #pragma unroll
        for (int nt = 0; nt < 8; ++nt) {
            acc[0][nt] = __builtin_amdgcn_mfma_f32_16x16x32_bf16(a0, bq[cb][nt], acc[0][nt], 0, 0, 0);
            acc[1][nt] = __builtin_amdgcn_mfma_f32_16x16x32_bf16(a1, bq[cb][nt], acc[1][nt], 0, 0, 0);
        }
    }

    // ---- per-tile: sigmoid -> gates LDS, tree -> A-frags, GEMM2, store
    float gbv[8];
    #pragma unroll
    for (int nt = 0; nt < 8; ++nt) {
        int col = 128 * wc + nt * 16 + l15;
        gbv[nt] = (col < 255) ? gb[col] : 0.0f;
    }

    for (int t = 0; t < 2; ++t) {
        __syncthreads();   // gates region free (previous tile's tree reads done)

        // phase 2: C/D layout col=lane&15, row=4q+reg
        #pragma unroll
        for (int nt = 0; nt < 8; ++nt) {
            const int col = 128 * wc + nt * 16 + l15;
            #pragma unroll
            for (int r = 0; r < 4; ++r) {
                const int rowl = 16 * wr + 4 * q + r;
                float v = acc[t][nt][r] + gbv[nt];
                gs[rowl * 258 + col] = 1.0f / (1.0f + __expf(-v));
            }
        }
        __syncthreads();

        // phase 3: leaf probs -> GEMM2 A-frags. A[m=lane&15][k=c*32+q*8+j], leaf l = k, group G = l>>3 = 4c+q
        const float* gr = gs + (16 * wr + l15) * 258;
        float g0v = gr[0];
        float t1v[2] = { g0v, 1.0f - g0v };
        float t2v[4], t3v[8];
        #pragma unroll
        for (int u = 0; u < 2; ++u) {
            float gl = gr[1 + u];
            t2v[2 * u] = t1v[u] * gl; t2v[2 * u + 1] = t1v[u] - t2v[2 * u];
        }
        #pragma unroll
        for (int u = 0; u < 4; ++u) {
            float gl = gr[3 + u];
            t3v[2 * u] = t2v[u] * gl; t3v[2 * u + 1] = t2v[u] - t3v[2 * u];
        }
        bf16x8 a2[8];
        #pragma unroll
        for (int c = 0; c < 8; ++c) {
            const int G = c * 4 + q;
            float p = t3v[c];
            float g3 = gr[7 + c];                    // level 3: node 7 + (G>>2), bit (G>>1)&1 = q>>1
            p = (q & 2) ? (p - p * g3) : (p * g3);
            float g4 = gr[15 + 2 * c + (q >> 1)];    // level 4: node 15 + (G>>1), bit G&1 = q&1
            p = (q & 1) ? (p - p * g4) : (p * g4);
            float g5 = gr[31 + G];
            float a0 = p * g5, a1 = p - a0;
            float g6a = gr[63 + 2 * G], g6b = gr[64 + 2 * G];
            float b00 = a0 * g6a, b01 = a0 - b00;
            float b10 = a1 * g6b, b11 = a1 - b10;
            float g70 = gr[127 + 4 * G], g71 = gr[128 + 4 * G];
            float g72 = gr[129 + 4 * G], g73 = gr[130 + 4 * G];
            float lf0 = b00 * g70, lf1 = b00 - lf0;
            float lf2 = b01 * g71, lf3 = b01 - lf2;
            float lf4 = b10 * g72, lf5 = b10 - lf4;
            float lf6 = b11 * g73, lf7 = b11 - lf6;
            union { bf16x8 v; uint32_t u[4]; } pk;
            pk.u[0] = pkbf(lf0, lf1);
            pk.u[1] = pkbf(lf2, lf3);
            pk.u[2] = pkbf(lf4, lf5);
            pk.u[3] = pkbf(lf6, lf7);
            a2[c] = pk.v;
        }

        // GEMM2: out_tile = leaf @ z^T, B-frags straight from L2-resident zb
        f32x4 acc2[8];
        #pragma unroll
        for (int i = 0; i < 8; ++i) acc2[i] = (f32x4){0.f, 0.f, 0.f, 0.f};
        #pragma unroll
        for (int nt = 0; nt < 8; ++nt) {
            const unsigned short* zrow = zb + (size_t)(128 * wc + nt * 16 + l15) * 256 + q * 8;
            #pragma unroll
            for (int c = 0; c < 8; ++c) {
                bf16x8 b = *(const bf16x8*)(zrow + c * 32);
                acc2[nt] = __builtin_amdgcn_mfma_f32_16x16x32_bf16(a2[c], b, acc2[nt], 0, 0, 0);
            }
        }

        // epilogue
        #pragma unroll
        for (int nt = 0; nt < 8; ++nt) {
            const int col = 128 * wc + nt * 16 + l15;
            #pragma unroll
            for (int r = 0; r < 4; ++r) {
                const int row = R0 + t * 64 + 16 * wr + 4 * q + r;
                out[(size_t)row * 256 + col] = acc2[nt][r];
            }
        }
    }
}

extern "C" void kernel_launch(void* const* d_in, const int* in_sizes, int n_in,
                              void* d_out, int out_size, void* d_ws, size_t ws_size,
                              hipStream_t stream) {
    const float* x  = (const float*)d_in[0];
    const float* gw = (const float*)d_in[1];
    const float* gb = (const float*)d_in[2];
    const float* z  = (const float*)d_in[3];
    float* outp = (float*)d_out;

    unsigned short* gwt = (unsigned short*)d_ws;     // 256*512 bf16 = 256 KB
    unsigned short* zbf = gwt + 256 * 512;           // 256*256 bf16 = 128 KB

    softtree_prep<<<96, 256, 0, stream>>>(gw, z, gwt, zbf);
    softtree_main<<<512, 512, 0, stream>>>(x, gb, gwt, zbf, outp);
}

// Round 3
// 284.554 us; speedup vs baseline: 1.1916x; 1.1916x over previous
//
#include <hip/hip_runtime.h>
#include <hip/hip_bf16.h>
#include <stdint.h>

// SoftTree: x(65536x512) f32, gw(512x255) f32, gb(255) f32, z(256x256) f32 -> out(65536x256) f32
// g = sigmoid(x@gw+gb); leaf = depth-8 tree products of g / (1-g); out = leaf @ z^T.
//
// R3: GEMM1 = counted-vmcnt global_load_lds pipeline (T3+T4), never draining vmcnt to 0.
//   - BK=32 chunks, 16 chunks. Per wave per chunk: 2 x-DMAs + 2 gw-DMAs (1KB each).
//   - x staged f32, 3-deep (issued 2 phases ahead); gw bf16, 2-deep (1 phase ahead, L2-resident).
//   - Per round: s_waitcnt vmcnt(2); s_barrier; sched_barrier(0); issue gw(k+1), x(k+2); compute k.
//   - LDS 80KB: xbuf[3] @0/16K/32K, gbuf[2] @48K/64K; gates (66KB) alias after GEMM1.
//   - XOR-swizzled LDS cells with pre-swizzled per-lane global DMA sources (linear LDS dest).
// Tile phase (sigmoid/tree/GEMM2/store) identical to the 125us baseline.

typedef short bf16x8 __attribute__((ext_vector_type(8)));
typedef float f32x4  __attribute__((ext_vector_type(4)));

__device__ __forceinline__ unsigned short f2bf(float f) {
    union { float f; uint32_t u; } c; c.f = f;
    uint32_t u = c.u;
    return (unsigned short)((u + 0x7FFFu + ((u >> 16) & 1u)) >> 16);
}

__device__ __forceinline__ uint32_t pkbf(float a, float b) {
    union { __hip_bfloat162 h; uint32_t u; } cv;
    cv.h = __float22bfloat162_rn(make_float2(a, b));   // v_cvt_pk_bf16_f32 on gfx950
    return cv.u;
}

// ---- prep: blocks 0..31 transpose gw (512x255 f32, gate-fast) -> gwt bf16 [gate][k] (256x512, row255=0)
//            blocks 32..95: z (256x256 f32) -> zb bf16
__global__ __launch_bounds__(256) void softtree_prep(
    const float* __restrict__ gw, const float* __restrict__ z,
    unsigned short* __restrict__ gwt, unsigned short* __restrict__ zb)
{
    if (blockIdx.x < 32) {
        __shared__ float tsm[64][65];
        const int k0 = (blockIdx.x >> 2) * 64;
        const int n0 = (blockIdx.x & 3) * 64;
        const int r = threadIdx.x >> 6;   // 0..3
        const int c = threadIdx.x & 63;   // 0..63
        const int n = n0 + c;
        #pragma unroll
        for (int i = 0; i < 16; ++i) {
            int kk = r + i * 4;
            tsm[kk][c] = (n < 255) ? gw[(size_t)(k0 + kk) * 255 + n] : 0.0f;
        }
        __syncthreads();
        #pragma unroll
        for (int i = 0; i < 16; ++i) {
            int nn = r + i * 4;           // local gate index
            gwt[(size_t)(n0 + nn) * 512 + k0 + c] = f2bf(tsm[c][nn]);
        }
    } else {
        int base = (blockIdx.x - 32) * 1024 + threadIdx.x * 4;
        const float4 v = *(const float4*)(z + base);
        ushort4 o;
        o.x = f2bf(v.x); o.y = f2bf(v.y); o.z = f2bf(v.z); o.w = f2bf(v.w);
        *(ushort4*)(zb + base) = o;
    }
}

// ---- main: 512 threads (8 waves), 2 row-tiles of 64 per block, grid 512, 2 blocks/CU.
__global__ __launch_bounds__(512, 4) void softtree_main(
    const float* __restrict__ x, const float* __restrict__ gb,
    const unsigned short* __restrict__ gwt, const unsigned short* __restrict__ zb,
    float* __restrict__ out)
{
    __shared__ char smraw[81920];
    float* gs = (float*)smraw;   // gates alias [0, 66048) after GEMM1

    const int tid  = threadIdx.x;
    const int lane = tid & 63;
    const int wv   = tid >> 6;
    const int q    = lane >> 4;
    const int l15  = lane & 15;
    const int wr   = wv & 3;
    const int wc   = wv >> 2;
    const int R0   = blockIdx.x * 128;

    // ---- gb preload FIRST, then drain vmcnt so the DMA FIFO accounting below stays exact.
    float gbv[8];
    #pragma unroll
    for (int nt = 0; nt < 8; ++nt) {
        int col = 128 * wc + nt * 16 + l15;
        gbv[nt] = (col < 255) ? gb[col] : 0.0f;
    }
    asm volatile("s_waitcnt vmcnt(0)" ::: "memory");

    // ---- DMA addressing.
    // x cell (row r 0..127, kgroup g 0..7 of 4 f32): LDS off = r*128 + (g^(r&7))*16 in xbuf.
    //   instr (wv,i): lane l stages row 16wv+8i+(l>>3), phys slot l&7 -> logical g=(l&7)^(l>>3).
    const float* xsrc0 = x + (size_t)(R0 + 16 * wv + (lane >> 3)) * 512
                           + (size_t)(((lane & 7) ^ (lane >> 3)) * 4);
    // gw cell (gate G 0..255, qg 0..3 of 8 bf16): LDS off = G*64 + (qg^(G&3))*16 in gbuf.
    //   instr (wv,i): lane l stages G = 32wv+16i+(l>>2), phys slot l&3 -> qg=(l&3)^((l>>2)&3).
    const unsigned short* gsrc0 = gwt + (size_t)(32 * wv + (lane >> 2)) * 512
                                      + (size_t)(((lane & 3) ^ ((lane >> 2) & 3)) * 8);
    const uint32_t xdst = (uint32_t)wv * 2048;            // + i*1024 + xb*16384
    const uint32_t gdst = 49152u + (uint32_t)wv * 2048;   // + i*1024 + gwb*16384

    #define ISSUE_X(kc, xb)                                                                    \
        do {                                                                                   \
            const float* s_ = xsrc0 + (kc) * 32;                                               \
            __builtin_amdgcn_global_load_lds(                                                  \
                (const __attribute__((address_space(1))) void*)(s_),                           \
                (__attribute__((address_space(3))) void*)(smraw + (xb) * 16384 + xdst),        \
                16, 0, 0);                                                                     \
            __builtin_amdgcn_global_load_lds(                                                  \
                (const __attribute__((address_space(1))) void*)(s_ + 8 * 512),                 \
                (__attribute__((address_space(3))) void*)(smraw + (xb) * 16384 + xdst + 1024), \
                16, 0, 0);                                                                     \
        } while (0)

    #define ISSUE_G(kc, gwb)                                                                   \
        do {                                                                                   \
            const unsigned short* s_ = gsrc0 + (kc) * 32;                                      \
            __builtin_amdgcn_global_load_lds(                                                  \
                (const __attribute__((address_space(1))) void*)(s_),                           \
                (__attribute__((address_space(3))) void*)(smraw + (gwb) * 16384 + gdst),       \
                16, 0, 0);                                                                     \
            __builtin_amdgcn_global_load_lds(                                                  \
                (const __attribute__((address_space(1))) void*)(s_ + 16 * 512),                \
                (__attribute__((address_space(3))) void*)(smraw + (gwb) * 16384 + gdst + 1024),\
                16, 0, 0);                                                                     \
        } while (0)

    f32x4 acc[2][8];
    #pragma unroll
    for (int t = 0; t < 2; ++t)
        #pragma unroll
        for (int i = 0; i < 8; ++i) acc[t][i] = (f32x4){0.f, 0.f, 0.f, 0.f};

    // ---- prologue: FIFO = [x0(2), gw0(2), x1(2)]
    ISSUE_X(0, 0);
    ISSUE_G(0, 0);
    ISSUE_X(1, 1);

    // ---- K-loop: 16 chunks of BK=32. Steady round k:
    //   wait vmcnt(2)  -> x(k), gw(k) landed; x(k+1) still in flight
    //   s_barrier      -> all waves' chunk-k staging complete; all done reading k-1 buffers
    //   issue gw(k+1) -> gbuf (k+1)&1 (freed), x(k+2) -> xbuf (k+2)%3 (freed)
    //   compute chunk k
    int xb = 0, gwb = 0;
    for (int kc = 0; kc < 15; ++kc) {
        asm volatile("s_waitcnt vmcnt(2)" ::: "memory");
        __builtin_amdgcn_s_barrier();
        __builtin_amdgcn_sched_barrier(0);

        ISSUE_G(kc + 1, gwb ^ 1);
        if (kc < 14) {
            int xb2 = xb + 2; if (xb2 >= 3) xb2 -= 3;
            ISSUE_X(kc + 2, xb2);
        }

        // compute chunk kc from xbuf[xb], gbuf[gwb]
        {
            const char* xbase = smraw + xb * 16384;
            const char* gbase = smraw + 49152 + gwb * 16384;
            bf16x8 a[2];
            #pragma unroll
            for (int t = 0; t < 2; ++t) {
                const char* ra = xbase + (64 * t + 16 * wr + l15) * 128;
                f32x4 lo = *(const f32x4*)(ra + (((2 * q)     ^ (l15 & 7)) * 16));
                f32x4 hi = *(const f32x4*)(ra + (((2 * q + 1) ^ (l15 & 7)) * 16));
                union { bf16x8 v; uint32_t u[4]; } pk;
                pk.u[0] = pkbf(lo[0], lo[1]); pk.u[1] = pkbf(lo[2], lo[3]);
                pk.u[2] = pkbf(hi[0], hi[1]); pk.u[3] = pkbf(hi[2], hi[3]);
                a[t] = pk.v;
            }
            __builtin_amdgcn_s_setprio(1);
            #pragma unroll
            for (int nt = 0; nt < 8; ++nt) {
                const bf16x8 b = *(const bf16x8*)(gbase + (128 * wc + nt * 16 + l15) * 64
                                                        + ((q ^ (l15 & 3)) * 16));
                acc[0][nt] = __builtin_amdgcn_mfma_f32_16x16x32_bf16(a[0], b, acc[0][nt], 0, 0, 0);
                acc[1][nt] = __builtin_amdgcn_mfma_f32_16x16x32_bf16(a[1], b, acc[1][nt], 0, 0, 0);
            }
            __builtin_amdgcn_s_setprio(0);
        }

        xb = (xb == 2) ? 0 : xb + 1;
        gwb ^= 1;
    }

    // ---- peeled last chunk (kc=15): only its own DMAs remain in flight
    asm volatile("s_waitcnt vmcnt(0)" ::: "memory");
    __builtin_amdgcn_s_barrier();
    __builtin_amdgcn_sched_barrier(0);
    {
        const char* xbase = smraw + xb * 16384;          // xb == 15%3 == 0
        const char* gbase = smraw + 49152 + gwb * 16384; // gwb == 15&1 == 1
        bf16x8 a[2];
        #pragma unroll
        for (int t = 0; t < 2; ++t) {
            const char* ra = xbase + (64 * t + 16 * wr + l15) * 128;
            f32x4 lo = *(const f32x4*)(ra + (((2 * q)     ^ (l15 & 7)) * 16));
            f32x4 hi = *(const f32x4*)(ra + (((2 * q + 1) ^ (l15 & 7)) * 16));
            union { bf16x8 v; uint32_t u[4]; } pk;
            pk.u[0] = pkbf(lo[0], lo[1]); pk.u[1] = pkbf(lo[2], lo[3]);
            pk.u[2] = pkbf(hi[0], hi[1]); pk.u[3] = pkbf(hi[2], hi[3]);
            a[t] = pk.v;
        }
        __builtin_amdgcn_s_setprio(1);
        #pragma unroll
        for (int nt = 0; nt < 8; ++nt) {
            const bf16x8 b = *(const bf16x8*)(gbase + (128 * wc + nt * 16 + l15) * 64
                                                    + ((q ^ (l15 & 3)) * 16));
            acc[0][nt] = __builtin_amdgcn_mfma_f32_16x16x32_bf16(a[0], b, acc[0][nt], 0, 0, 0);
            acc[1][nt] = __builtin_amdgcn_mfma_f32_16x16x32_bf16(a[1], b, acc[1][nt], 0, 0, 0);
        }
        __builtin_amdgcn_s_setprio(0);
    }

    #undef ISSUE_X
    #undef ISSUE_G

    // ---- per-tile: sigmoid -> gates LDS, tree -> A-frags, GEMM2, store (unchanged from 125us baseline)
    for (int t = 0; t < 2; ++t) {
        __syncthreads();   // staging buffers free (all waves done reading) / prev tile's tree reads done

        // phase 2: C/D layout col=lane&15, row=4q+reg
        #pragma unroll
        for (int nt = 0; nt < 8; ++nt) {
            const int col = 128 * wc + nt * 16 + l15;
            #pragma unroll
            for (int r = 0; r < 4; ++r) {
                const int rowl = 16 * wr + 4 * q + r;
                float v = acc[t][nt][r] + gbv[nt];
                gs[rowl * 258 + col] = 1.0f / (1.0f + __expf(-v));
            }
        }
        __syncthreads();

        // phase 3: leaf probs -> GEMM2 A-frags. A[m=lane&15][k=c*32+q*8+j], leaf l = k, group G = l>>3 = 4c+q
        const float* gr = gs + (16 * wr + l15) * 258;
        float g0v = gr[0];
        float t1v[2] = { g0v, 1.0f - g0v };
        float t2v[4], t3v[8];
        #pragma unroll
        for (int u = 0; u < 2; ++u) {
            float gl = gr[1 + u];
            t2v[2 * u] = t1v[u] * gl; t2v[2 * u + 1] = t1v[u] - t2v[2 * u];
        }
        #pragma unroll
        for (int u = 0; u < 4; ++u) {
            float gl = gr[3 + u];
            t3v[2 * u] = t2v[u] * gl; t3v[2 * u + 1] = t2v[u] - t3v[2 * u];
        }
        bf16x8 a2[8];
        #pragma unroll
        for (int c = 0; c < 8; ++c) {
            const int G = c * 4 + q;
            float p = t3v[c];
            float g3 = gr[7 + c];                    // level 3: node 7 + (G>>2), bit (G>>1)&1 = q>>1
            p = (q & 2) ? (p - p * g3) : (p * g3);
            float g4 = gr[15 + 2 * c + (q >> 1)];    // level 4: node 15 + (G>>1), bit G&1 = q&1
            p = (q & 1) ? (p - p * g4) : (p * g4);
            float g5 = gr[31 + G];
            float a0 = p * g5, a1 = p - a0;
            float g6a = gr[63 + 2 * G], g6b = gr[64 + 2 * G];
            float b00 = a0 * g6a, b01 = a0 - b00;
            float b10 = a1 * g6b, b11 = a1 - b10;
            float g70 = gr[127 + 4 * G], g71 = gr[128 + 4 * G];
            float g72 = gr[129 + 4 * G], g73 = gr[130 + 4 * G];
            float lf0 = b00 * g70, lf1 = b00 - lf0;
            float lf2 = b01 * g71, lf3 = b01 - lf2;
            float lf4 = b10 * g72, lf5 = b10 - lf4;
            float lf6 = b11 * g73, lf7 = b11 - lf6;
            union { bf16x8 v; uint32_t u[4]; } pk;
            pk.u[0] = pkbf(lf0, lf1);
            pk.u[1] = pkbf(lf2, lf3);
            pk.u[2] = pkbf(lf4, lf5);
            pk.u[3] = pkbf(lf6, lf7);
            a2[c] = pk.v;
        }

        // GEMM2: out_tile = leaf @ z^T, B-frags straight from L2-resident zb
        f32x4 acc2[8];
        #pragma unroll
        for (int i = 0; i < 8; ++i) acc2[i] = (f32x4){0.f, 0.f, 0.f, 0.f};
        __builtin_amdgcn_s_setprio(1);
        #pragma unroll
        for (int nt = 0; nt < 8; ++nt) {
            const unsigned short* zrow = zb + (size_t)(128 * wc + nt * 16 + l15) * 256 + q * 8;
            #pragma unroll
            for (int c = 0; c < 8; ++c) {
                bf16x8 b = *(const bf16x8*)(zrow + c * 32);
                acc2[nt] = __builtin_amdgcn_mfma_f32_16x16x32_bf16(a2[c], b, acc2[nt], 0, 0, 0);
            }
        }
        __builtin_amdgcn_s_setprio(0);

        // epilogue
        #pragma unroll
        for (int nt = 0; nt < 8; ++nt) {
            const int col = 128 * wc + nt * 16 + l15;
            #pragma unroll
            for (int r = 0; r < 4; ++r) {
                const int row = R0 + t * 64 + 16 * wr + 4 * q + r;
                out[(size_t)row * 256 + col] = acc2[nt][r];
            }
        }
    }
}

extern "C" void kernel_launch(void* const* d_in, const int* in_sizes, int n_in,
                              void* d_out, int out_size, void* d_ws, size_t ws_size,
                              hipStream_t stream) {
    const float* x  = (const float*)d_in[0];
    const float* gw = (const float*)d_in[1];
    const float* gb = (const float*)d_in[2];
    const float* z  = (const float*)d_in[3];
    float* outp = (float*)d_out;

    unsigned short* gwt = (unsigned short*)d_ws;     // 256*512 bf16 = 256 KB
    unsigned short* zbf = gwt + 256 * 512;           // 256*256 bf16 = 128 KB

    softtree_prep<<<96, 256, 0, stream>>>(gw, z, gwt, zbf);
    softtree_main<<<512, 512, 0, stream>>>(x, gb, gwt, zbf, outp);
}